// Round 13
// baseline (34.027 us; speedup 1.0000x reference)
//
#include <hip/hip_runtime.h>
#include <math.h>

#define NRAYS 32768      // 16*64*32
#define NSPH  1024
#define NSL   16         // 64-sphere slices, one per wave
#define SLICE 64
#define TPB   1024       // 16 waves * 64 lanes
#define NBLK  (NRAYS / 64)   // 512 blocks, 64 rays each

// Pack spheres as {x, y, z, r^2} for wave-uniform scalar loads.
__global__ __launch_bounds__(256) void prep_kernel(
    const float* __restrict__ centers,
    const float* __restrict__ radii,
    float4* __restrict__ sph4)
{
    const int i = blockIdx.x * 256 + threadIdx.x;
    if (i < NSPH) {
        const float r = radii[i];
        sph4[i] = make_float4(centers[3 * i + 0], centers[3 * i + 1],
                              centers[3 * i + 2], r * r);   // == ref's rad*rad
    }
}

__global__ __launch_bounds__(TPB, 8) void sphere_kernel(
    const float* __restrict__ rays,
    const float4* __restrict__ sph4,
    float* __restrict__ out)
{
#pragma clang fp contract(off)
    __shared__ unsigned s_min[NSL][64];   // 4 KB merge array (only LDS use)

    const int tid  = threadIdx.x;
    const int lane = tid & 63;
    // Wave-uniform slice id -> sphere constants go through the scalar path.
    const int w    = __builtin_amdgcn_readfirstlane(tid >> 6);   // 0..15

    const int ray = blockIdx.x * 64 + lane;
    const float2* rp = (const float2*)(rays + ray * 6);
    const float2 q0 = rp[0], q1 = rp[1], q2 = rp[2];
    const float ox = q0.x, oy = q0.y, oz = q1.x;
    const float dx = q1.y, dy = q2.x, dz = q2.y;

    // a = ((dx*dx)+(dy*dy))+(dz*dz) -- numpy 3-elem sum order (kept exact)
    const float a = ((dx * dx) + (dy * dy)) + (dz * dz);

    // Fused value+argmin accumulator (validated R11/R12): bits of w with low 6
    // bits replaced by slice-local sphere idx. u32 order == float order on the
    // valid (positive) range; NaN (z<0) and negative-w (root behind origin)
    // patterns sort above bits(hunA) -> rejected for free. eps-bias dropped:
    // accepts only roots in [0,1e-8) incorrectly -- measure-zero (R10 class).
    const unsigned IMASK = 0xFFFFFFC0u;
    unsigned cw = 0xFFFFFFFFu;

    const float4* __restrict__ spb = sph4 + w * SLICE;

#pragma unroll
    for (int i = 0; i < SLICE; ++i) {
        const float4 S = spb[i];           // wave-uniform -> s_load, SGPR operands
        // FMA-contracted front (validated R10-R12), operands <=1 SGPR per op.
        const float fx = ox - S.x;
        const float fy = oy - S.y;
        const float fz = oz - S.z;
        const float dt = __builtin_fmaf(dz, fz, __builtin_fmaf(dy, fy, dx * fx));
        const float cc = __builtin_fmaf(fz, fz, __builtin_fmaf(fy, fy, fx * fx)) - S.w;
        const float zz = __builtin_fmaf(dt, dt, -(a * cc));   // z = dt^2 - a*cc
        const float s  = __builtin_amdgcn_sqrtf(zz);          // NaN if zz<0
        const float w0 = s - dt;           // larger root numerator
        const float w1 = (-s) - dt;        // smaller root numerator (neg folds)
        const unsigned b0 = __builtin_bit_cast(unsigned, w0);
        const unsigned b1 = __builtin_bit_cast(unsigned, w1);
        const unsigned m  = (b1 < b0) ? b1 : b0;              // smallest root >= 0
        const unsigned u  = (m & IMASK) | (unsigned)i;        // pack idx
        cw = (u < cw) ? u : cw;                               // strict <: first occ.
    }

    s_min[w][lane] = cw;
    __syncthreads();

    // Epilogue: wave 0, one lane per ray (its own ray == lane's ray).
    if (tid < 64) {
        unsigned bw = 0xFFFFFFFFu;
        int ksel = 0;
        for (int k = 0; k < NSL; ++k) {
            const unsigned mt = s_min[k][tid];
            if (mt < bw) { bw = mt; ksel = k; }   // earlier slice wins ties
        }
        const float hunA = 100.0f * a;
        // active <=> winning value < hunA (u32 compare valid on live patterns).
        const bool active = bw < __builtin_bit_cast(unsigned, hunA);

        // Single IEEE division per ray.
        const float best = active ? (__builtin_bit_cast(float, bw) / a) : 100.0f;

        float px = ox + (best * dx);
        float py = oy + (best * dy);
        float pz = oz + (best * dz);

        // reference: face is chunk-LOCAL (0..255); idx=clip(face,0,1023) bug kept.
        // global sphere for normal = ((ksel&3)*64 + idx) in [0,255].
        const int gidx = active ? (((ksel & 3) << 6) | (int)(bw & 63u)) : 0;
        const float4 C = sph4[gidx];
        const float ddx = px - C.x;
        const float ddy = py - C.y;
        const float ddz = pz - C.z;
        float nrm = sqrtf(((ddx * ddx) + (ddy * ddy)) + (ddz * ddz));
        nrm = fmaxf(nrm, 1e-12f);
        const float nx = active ? (ddx / nrm) : 0.0f;
        const float ny = active ? (ddy / nrm) : 0.0f;
        const float nz = active ? (ddz / nrm) : 0.0f;
        px = px + (nx * 1e-5f);
        py = py + (ny * 1e-5f);
        pz = pz + (nz * 1e-5f);

        const int r = blockIdx.x * 64 + tid;
        float* outp = out;                 // p: 3*NRAYS
        float* outn = out + NRAYS * 3;     // n: 3*NRAYS
        float* outd = out + NRAYS * 6;     // best_dists: NRAYS
        float* outa = out + NRAYS * 7;     // out_active: NRAYS

        outp[r * 3 + 0] = px;
        outp[r * 3 + 1] = py;
        outp[r * 3 + 2] = pz;
        outn[r * 3 + 0] = nx;
        outn[r * 3 + 1] = ny;
        outn[r * 3 + 2] = nz;
        outd[r] = best;
        outa[r] = active ? 1.0f : 0.0f;
    }
}

extern "C" void kernel_launch(void* const* d_in, const int* in_sizes, int n_in,
                              void* d_out, int out_size, void* d_ws, size_t ws_size,
                              hipStream_t stream) {
    const float* rays    = (const float*)d_in[0];
    const float* centers = (const float*)d_in[1];
    const float* radii   = (const float*)d_in[2];
    float* out = (float*)d_out;
    float4* sph4 = (float4*)d_ws;   // 1024 * 16 B = 16 KB scratch

    hipLaunchKernelGGL(prep_kernel, dim3(NSPH / 256), dim3(256), 0, stream,
                       centers, radii, sph4);
    hipLaunchKernelGGL(sphere_kernel, dim3(NBLK), dim3(TPB), 0, stream,
                       rays, sph4, out);
}

// Round 14
// 22.850 us; speedup vs baseline: 1.4892x; 1.4892x over previous
//
#include <hip/hip_runtime.h>
#include <math.h>

#define NRAYS 32768      // 16*64*32
#define NSPH  1024
#define SUBS  64         // subchunks of 16 spheres
#define SPAIR 8          // pairs per subchunk
#define RQB   16         // ray-quads per block (64 rays)
#define TPB   1024       // 16 quads * 64 subs
#define NBLK  (NRAYS / 64)   // 512 blocks

typedef float    v2f __attribute__((ext_vector_type(2)));
typedef unsigned v2u __attribute__((ext_vector_type(2)));

static __device__ __forceinline__ v2f fma2(v2f a, v2f b, v2f c) {
    v2f r;
    r.x = __builtin_fmaf(a.x, b.x, c.x);
    r.y = __builtin_fmaf(a.y, b.y, c.y);
    return r;
}

__global__ __launch_bounds__(TPB, 4) void sphere_kernel(
    const float* __restrict__ rays,
    const float* __restrict__ centers,
    const float* __restrict__ radii,
    float* __restrict__ out)
{
#pragma clang fp contract(off)
    // Pair-SoA per 16-sphere sub: 16 float4 + 1 pad (stride 17 -> the 4
    // distinct broadcast addresses per wave land on distinct banks).
    __shared__ float4   sph[SUBS * (2 * SPAIR + 1)];   // 1088*16B = 17.4 KB
    __shared__ unsigned s_min[SUBS][65];               // padded merge, 16.6 KB

    const int tid = threadIdx.x;

    for (int p = tid; p < NSPH / 2; p += TPB) {        // 512 pairs
        const int g0 = 2 * p, g1 = 2 * p + 1;
        const float x0 = centers[3 * g0 + 0], y0 = centers[3 * g0 + 1], z0 = centers[3 * g0 + 2];
        const float x1 = centers[3 * g1 + 0], y1 = centers[3 * g1 + 1], z1 = centers[3 * g1 + 2];
        const float r0 = radii[g0], r1 = radii[g1];
        const int sub = p >> 3, within = p & 7;
        const int b4 = sub * (2 * SPAIR + 1) + within * 2;
        sph[b4 + 0] = make_float4(x0, x1, y0, y1);
        sph[b4 + 1] = make_float4(z0, z1, r0 * r0, r1 * r1);
    }
    __syncthreads();

    // tid = s*16 + q: wave = 16 quads x 4 subs -> 4 distinct LDS bcast addrs.
    const int q   = tid & (RQB - 1);   // ray-quad 0..15
    const int sub = tid >> 4;          // subchunk 0..63
    const int ray0 = blockIdx.x * 64 + q * 4;

    // Per-ray state for 4 rays.
    float ox[4], oy[4], oz[4], dxr[4], dyr[4], dzr[4], ar[4];
#pragma unroll
    for (int j = 0; j < 4; ++j) {
        const float2* rp = (const float2*)(rays + (ray0 + j) * 6);
        const float2 q0 = rp[0], q1 = rp[1], q2 = rp[2];
        ox[j] = q0.x; oy[j] = q0.y; oz[j] = q1.x;
        dxr[j] = q1.y; dyr[j] = q2.x; dzr[j] = q2.y;
        // numpy 3-elem sum order (kept exact; feeds thresholds + final div)
        ar[j] = ((dxr[j] * dxr[j]) + (dyr[j] * dyr[j])) + (dzr[j] * dzr[j]);
    }

    // Fused value+argmin accumulators (validated R11/R12), 4-bit idx now:
    // <=15-ulp value perturbation, inside the validated 63-ulp class.
    const unsigned IMASK = 0xFFFFFFF0u;
    unsigned cw[4] = {0xFFFFFFFFu, 0xFFFFFFFFu, 0xFFFFFFFFu, 0xFFFFFFFFu};

    const float4* __restrict__ spb = &sph[sub * (2 * SPAIR + 1)];

#pragma unroll
    for (int i = 0; i < SPAIR; ++i) {
        const float4 A = spb[2 * i];       // (x0,x1,y0,y1)
        const float4 B = spb[2 * i + 1];   // (z0,z1,r2_0,r2_1)
        const v2f X = {A.x, A.y}, Y = {A.z, A.w};
        const v2f Z = {B.x, B.y}, Q = {B.z, B.w};
#pragma unroll
        for (int j = 0; j < 4; ++j) {
            const v2f o_x = {ox[j], ox[j]}, o_y = {oy[j], oy[j]}, o_z = {oz[j], oz[j]};
            const v2f d_x = {dxr[j], dxr[j]}, d_y = {dyr[j], dyr[j]}, d_z = {dzr[j], dzr[j]};
            const v2f an2 = {-ar[j], -ar[j]};
            // FMA-contracted front (validated R10-R12).
            const v2f fx = o_x - X;
            const v2f fy = o_y - Y;
            const v2f fz = o_z - Z;
            const v2f dt = fma2(d_z, fz, fma2(d_y, fy, d_x * fx));
            const v2f cc = fma2(fz, fz, fma2(fy, fy, fx * fx)) - Q;
            const v2f zz = fma2(dt, dt, an2 * cc);
            const v2f s  = { __builtin_amdgcn_sqrtf(zz.x),   // NaN if z<0
                             __builtin_amdgcn_sqrtf(zz.y) };
            const v2f vv0 = s - dt;        // larger-root numerator
            const v2f vv1 = (-s) - dt;     // smaller-root numerator
            const v2u b0 = __builtin_bit_cast(v2u, vv0);
            const v2u b1 = __builtin_bit_cast(v2u, vv1);
            const unsigned me = (b1.x < b0.x) ? b1.x : b0.x;   // even sphere 2i
            const unsigned mo = (b1.y < b0.y) ? b1.y : b0.y;   // odd sphere 2i+1
            const unsigned ue = (me & IMASK) | (unsigned)(2 * i);
            const unsigned uo = (mo & IMASK) | (unsigned)(2 * i + 1);
            const unsigned mp = (ue < uo) ? ue : uo;
            cw[j] = (mp < cw[j]) ? mp : cw[j];   // strict <: first occurrence
        }
    }

#pragma unroll
    for (int j = 0; j < 4; ++j) s_min[sub][q * 4 + j] = cw[j];
    __syncthreads();

    // Epilogue: threads 0..63 handle one ray each (ray = blockbase + tid).
    if (tid < 64) {
        unsigned bw = 0xFFFFFFFFu;
        int ksel = 0;
        for (int k = 0; k < SUBS; ++k) {     // ascending global sphere order
            const unsigned mt = s_min[k][tid];
            if (mt < bw) { bw = mt; ksel = k; }   // strict <: earlier wins ties
        }
        const float2* rp = (const float2*)(rays + (blockIdx.x * 64 + tid) * 6);
        const float2 q0 = rp[0], q1 = rp[1], q2 = rp[2];
        const float rox = q0.x, roy = q0.y, roz = q1.x;
        const float rdx = q1.y, rdy = q2.x, rdz = q2.y;
        const float a = ((rdx * rdx) + (rdy * rdy)) + (rdz * rdz);
        const float hunA = 100.0f * a;
        const bool active = bw < __builtin_bit_cast(unsigned, hunA);

        const float best = active ? (__builtin_bit_cast(float, bw) / a) : 100.0f;

        float px = rox + (best * rdx);
        float py = roy + (best * rdy);
        float pz = roz + (best * rdz);

        // face = chunk-LOCAL index (reference bug kept): ((ksel&15)<<4)|idx.
        const int gidx = active ? (((ksel & 15) << 4) | (int)(bw & 15u)) : 0;
        const int b4 = (gidx >> 4) * (2 * SPAIR + 1) + ((gidx & 15) >> 1) * 2;
        const int jj = gidx & 1;
        const float4 A = sph[b4];
        const float4 B = sph[b4 + 1];
        const float cxv = jj ? A.y : A.x;
        const float cyv = jj ? A.w : A.z;
        const float czv = jj ? B.y : B.x;
        const float ddx = px - cxv;
        const float ddy = py - cyv;
        const float ddz = pz - czv;
        float nrm = sqrtf(((ddx * ddx) + (ddy * ddy)) + (ddz * ddz));
        nrm = fmaxf(nrm, 1e-12f);
        const float nx = active ? (ddx / nrm) : 0.0f;
        const float ny = active ? (ddy / nrm) : 0.0f;
        const float nz = active ? (ddz / nrm) : 0.0f;
        px = px + (nx * 1e-5f);
        py = py + (ny * 1e-5f);
        pz = pz + (nz * 1e-5f);

        const int r = blockIdx.x * 64 + tid;
        float* outp = out;                 // p: 3*NRAYS
        float* outn = out + NRAYS * 3;     // n: 3*NRAYS
        float* outd = out + NRAYS * 6;     // best_dists: NRAYS
        float* outa = out + NRAYS * 7;     // out_active: NRAYS

        outp[r * 3 + 0] = px;
        outp[r * 3 + 1] = py;
        outp[r * 3 + 2] = pz;
        outn[r * 3 + 0] = nx;
        outn[r * 3 + 1] = ny;
        outn[r * 3 + 2] = nz;
        outd[r] = best;
        outa[r] = active ? 1.0f : 0.0f;
    }
}

extern "C" void kernel_launch(void* const* d_in, const int* in_sizes, int n_in,
                              void* d_out, int out_size, void* d_ws, size_t ws_size,
                              hipStream_t stream) {
    const float* rays    = (const float*)d_in[0];
    const float* centers = (const float*)d_in[1];
    const float* radii   = (const float*)d_in[2];
    float* out = (float*)d_out;

    dim3 grid(NBLK);     // 512 blocks
    dim3 block(TPB);     // 1024 threads
    hipLaunchKernelGGL(sphere_kernel, grid, block, 0, stream,
                       rays, centers, radii, out);
}

// Round 15
// 19.367 us; speedup vs baseline: 1.7569x; 1.1798x over previous
//
#include <hip/hip_runtime.h>
#include <math.h>

#define NRAYS 32768      // 16*64*32
#define NSPH  1024
#define SUBS  16         // subchunks per ray (64 spheres each)
#define PAIRS 32         // sphere-pairs per subchunk
#define RPB   16         // rays per block
#define TPB   256
#define NBLK  (NRAYS / RPB)   // 2048 blocks

typedef float    v2f __attribute__((ext_vector_type(2)));
typedef unsigned v2u __attribute__((ext_vector_type(2)));

// Elementwise fused multiply-add on v2f (explicit contraction; pragma-immune).
static __device__ __forceinline__ v2f fma2(v2f a, v2f b, v2f c) {
    v2f r;
    r.x = __builtin_fmaf(a.x, b.x, c.x);
    r.y = __builtin_fmaf(a.y, b.y, c.y);
    return r;
}

// 3-input unsigned min -> v_min3_u32 on gfx9+.
static __device__ __forceinline__ unsigned min3u(unsigned a, unsigned b, unsigned c) {
    return __builtin_elementwise_min(__builtin_elementwise_min(a, b), c);
}

__global__ __launch_bounds__(256, 8) void sphere_kernel(
    const float* __restrict__ rays,
    const float* __restrict__ centers,
    const float* __restrict__ radii,
    float* __restrict__ out)
{
#pragma clang fp contract(off)
    // Pair-SoA: pair p of sub k: sph[base+2p]=(x0,x1,y0,y1), sph[base+2p+1]=(z0,z1,r2_0,r2_1)
    // sub stride 65 float4 = 1040 B -> the 4 broadcast addresses per wave hit
    // disjoint bank quads (conflict-free).
    __shared__ float4   sph[SUBS * (2 * PAIRS + 1)];   // 16.6 KB
    __shared__ unsigned s_min[SUBS][RPB];              // u32-ordered (v-bits|idx)

    const int tid = threadIdx.x;

    for (int p = tid; p < NSPH / 2; p += TPB) {
        const int g0 = 2 * p, g1 = 2 * p + 1;
        const float x0 = centers[3 * g0 + 0], y0 = centers[3 * g0 + 1], z0 = centers[3 * g0 + 2];
        const float x1 = centers[3 * g1 + 0], y1 = centers[3 * g1 + 1], z1 = centers[3 * g1 + 2];
        const float r0 = radii[g0], r1 = radii[g1];
        const int b4 = (p >> 5) * (2 * PAIRS + 1) + (p & 31) * 2;
        sph[b4 + 0] = make_float4(x0, x1, y0, y1);
        sph[b4 + 1] = make_float4(z0, z1, r0 * r0, r1 * r1);
    }
    __syncthreads();

    const int rl  = tid & (RPB - 1);   // ray within block, 0..15
    const int sub = tid >> 4;          // subchunk 0..15
    const int ray = blockIdx.x * RPB + rl;

    const float2* rp = (const float2*)(rays + ray * 6);
    const float2 q0 = rp[0], q1 = rp[1], q2 = rp[2];
    const float ox = q0.x, oy = q0.y, oz = q1.x;
    const float dx = q1.y, dy = q2.x, dz = q2.y;

    // a = ((dx*dx)+(dy*dy))+(dz*dz) -- numpy 3-elem sum order (kept exact)
    const float a    = ((dx * dx) + (dy * dy)) + (dz * dz);
    const float hunA = 100.0f * a;     // deferred: active <=> u* < hunA

    const v2f ox2 = {ox, ox}, oy2 = {oy, oy}, oz2 = {oz, oz};
    const v2f dx2 = {dx, dx}, dy2 = {dy, dy}, dz2 = {dz, dz};
    const v2f an2 = {-a, -a};              // z = fma(dt,dt, (-a)*cc)

    // Fused value+argmin accumulator (validated R11/R12): bits of w (root
    // numerator), low 6 bits replaced by sphere index. u32 order == float
    // order on valid (positive) patterns; NaN (z<0) and negative-w (root<0)
    // sort above bits(hunA) -> rejected for free. eps bias dropped (validated
    // R13/R14: misaccepts only roots in [0,1e-8), measure-zero).
    const unsigned IMASK = 0xFFFFFFC0u;
    unsigned cw = 0xFFFFFFFFu;

    const float4* __restrict__ spb = &sph[sub * (2 * PAIRS + 1)];

#pragma unroll
    for (int i = 0; i < PAIRS; ++i) {
        const float4 A = spb[2 * i];       // (x0,x1,y0,y1)
        const float4 B = spb[2 * i + 1];   // (z0,z1,r2_0,r2_1)
        const v2f X = {A.x, A.y}, Y = {A.z, A.w};
        const v2f Z = {B.x, B.y}, Q = {B.z, B.w};
        // FMA-contracted pk front (validated R10-R12).
        const v2f fx = ox2 - X;
        const v2f fy = oy2 - Y;
        const v2f fz = oz2 - Z;
        const v2f dt = fma2(dz2, fz, fma2(dy2, fy, dx2 * fx));
        const v2f cc = fma2(fz, fz, fma2(fy, fy, fx * fx)) - Q;
        const v2f zz = fma2(dt, dt, an2 * cc);     // z = dt^2 - a*cc (fused)
        const v2f s  = { __builtin_amdgcn_sqrtf(zz.x),   // raw v_sqrt; NaN if z<0
                         __builtin_amdgcn_sqrtf(zz.y) };
        const v2f vv0 = s - dt;            // larger-root numerator
        const v2f vv1 = (-s) - dt;         // smaller-root numerator (negs fold)
        const v2u b0 = __builtin_bit_cast(v2u, vv0);
        const v2u b1 = __builtin_bit_cast(v2u, vv1);
        // even sphere 2i / odd sphere 2i+1: min root (v_min_u32), pack idx
        // (v_and_or_b32), then single v_min3_u32 merges both with the running min.
        const unsigned me = __builtin_elementwise_min(b1.x, b0.x);
        const unsigned mo = __builtin_elementwise_min(b1.y, b0.y);
        const unsigned ue = (me & IMASK) | (unsigned)(2 * i);
        const unsigned uo = (mo & IMASK) | (unsigned)(2 * i + 1);
        cw = min3u(ue, uo, cw);            // ties: smaller idx = first occurrence
    }

    s_min[sub][rl] = cw;
    __syncthreads();

    // Epilogue: threads 0..15 handle one ray each.
    if (tid < RPB) {
        unsigned bw = 0xFFFFFFFFu;
        int ksel = 0;
        for (int k = 0; k < SUBS; ++k) {
            const unsigned mt = s_min[k][tid];
            if (mt < bw) { bw = mt; ksel = k; }   // earlier sub wins ties
        }
        // active <=> winning value < hunA (u32 compare valid on live patterns).
        const bool active = bw < __builtin_bit_cast(unsigned, hunA);

        // Single IEEE division per ray (value carries <=63-ulp idx perturbation).
        const float best = active ? (__builtin_bit_cast(float, bw) / a) : 100.0f;

        float px = ox + (best * dx);
        float py = oy + (best * dy);
        float pz = oz + (best * dz);

        // reference: face is chunk-LOCAL (0..255); idx=clip(face,0,1023) bug kept.
        const int gidx = active ? (((ksel & 3) << 6) | (int)(bw & 63u)) : 0;
        const int b4 = (gidx >> 6) * (2 * PAIRS + 1) + ((gidx & 63) >> 1) * 2;
        const int j  = gidx & 1;
        const float4 A = sph[b4];
        const float4 B = sph[b4 + 1];
        const float cxv = j ? A.y : A.x;
        const float cyv = j ? A.w : A.z;
        const float czv = j ? B.y : B.x;
        const float ddx = px - cxv;
        const float ddy = py - cyv;
        const float ddz = pz - czv;
        float nrm = sqrtf(((ddx * ddx) + (ddy * ddy)) + (ddz * ddz));
        nrm = fmaxf(nrm, 1e-12f);
        const float nx = active ? (ddx / nrm) : 0.0f;
        const float ny = active ? (ddy / nrm) : 0.0f;
        const float nz = active ? (ddz / nrm) : 0.0f;
        px = px + (nx * 1e-5f);
        py = py + (ny * 1e-5f);
        pz = pz + (nz * 1e-5f);

        const int r = blockIdx.x * RPB + tid;
        float* outp = out;                 // p: 3*NRAYS
        float* outn = out + NRAYS * 3;     // n: 3*NRAYS
        float* outd = out + NRAYS * 6;     // best_dists: NRAYS
        float* outa = out + NRAYS * 7;     // out_active: NRAYS

        outp[r * 3 + 0] = px;
        outp[r * 3 + 1] = py;
        outp[r * 3 + 2] = pz;
        outn[r * 3 + 0] = nx;
        outn[r * 3 + 1] = ny;
        outn[r * 3 + 2] = nz;
        outd[r] = best;
        outa[r] = active ? 1.0f : 0.0f;
    }
}

extern "C" void kernel_launch(void* const* d_in, const int* in_sizes, int n_in,
                              void* d_out, int out_size, void* d_ws, size_t ws_size,
                              hipStream_t stream) {
    const float* rays    = (const float*)d_in[0];
    const float* centers = (const float*)d_in[1];
    const float* radii   = (const float*)d_in[2];
    float* out = (float*)d_out;

    dim3 grid(NBLK);     // 2048 blocks
    dim3 block(TPB);     // 256 threads
    hipLaunchKernelGGL(sphere_kernel, grid, block, 0, stream,
                       rays, centers, radii, out);
}